// Round 3
// baseline (203.106 us; speedup 1.0000x reference)
//
#include <hip/hip_runtime.h>
#include <stdint.h>

// DVH global loss, MI355X.
// B=4 batches, N=2^21 voxels/batch, 500 bins over [0,75].
// loss = mean_{b,j} ( suffix_sum_{k>j}(hist_p[b]-hist_g[b])[k] / (maskcount_b+1e-6) )^2
// Only the DIFFERENCE histogram matters: d[i] = hist_p[i] - hist_g[i] (exact in ints).
//
// R1: device fence in fused kernel -> per-wave L2 writeback -> 201 us. Reverted.
// R2: fence-free last-block protocol -> 41.5 us fused kernel, neutral total.
// R3: counters showed Occupancy 59%, VALUBusy 23%, eff BW 2.4 TB/s -> NOT
// BW-bound; straggler imbalance (grid == residency: 2x 1024-thr blocks/CU,
// one-shot threads, no backfill; L3-hit blocks finish 2-3x earlier than
// HBM-miss blocks and their CUs idle). Fix: 4096 x 256-thread blocks
// (8 resident/CU + 2x oversubscription queue -> HW dispatcher backfills).
// Reduce rewritten for 256 threads: wave w owns batch w, register-chunk scan.

#define NBINS 500
#define NHIST 501          // searchsorted index c in [0,500]; c>=1 for d>=0
#define BATCH 4
#define NPB (1 << 21)      // elements per batch
#define VPB (NPB / 4)      // float4 per batch (524288)
#define THREADS 256
#define F4PT 2             // float4 per array per thread
#define BPB (VPB / (THREADS * F4PT))   // 1024 blocks per batch
#define TOTAL_BLOCKS (BPB * BATCH)     // 4096

// workspace layout (int32):
//   hist_diff : [b*512 + i], i<501, b<4      (offset 0)
//   maskcount : [2048 + b]
//   done ctr  : [2052]
#define MC_OFF 2048
#define CTR_OFF 2052
#define WS_INTS 2056

__device__ __forceinline__ int bin_of(float d) {
    // c = # of fp32 bins k*STEP that are <= d  (jnp.linspace(0,75,500),
    // searchsorted side='right'); d >= 0 guaranteed.
    const float STEP = 75.0f / 499.0f;
    const float INV  = 499.0f / 75.0f;
    int k = (int)(d * INV);
    if (k > 499) k = 499;
    if ((float)k * STEP > d) --k;
    else if (k < 499 && (float)(k + 1) * STEP <= d) ++k;
    if ((float)k * STEP > d) --k;   // safety second pass (k>=0 since bins[0]=0<=d)
    return k + 1;                   // in [1,500]
}

__global__ __launch_bounds__(THREADS) void dvh_fused_kernel(
        const float4* __restrict__ dp, const float4* __restrict__ dg,
        const float4* __restrict__ dm, int* __restrict__ ws,
        float* __restrict__ out) {
    __shared__ int shd[NHIST];
    __shared__ unsigned int smc;
    __shared__ int lastflag;
    __shared__ float facc[BATCH];

    const int b = blockIdx.y;
    const int t = threadIdx.x;
    for (int i = t; i < NHIST; i += THREADS) shd[i] = 0;
    if (t == 0) smc = 0u;
    __syncthreads();

    // 6 independent vmem loads issued before any use (latency hiding via ILP;
    // TLP from 8 resident blocks/CU covers the rest).
    const size_t base = (size_t)b * VPB + (size_t)blockIdx.x * (THREADS * F4PT) + t;
    float4 m0 = dm[base]; float4 m1 = dm[base + THREADS];
    float4 p0 = dp[base]; float4 p1 = dp[base + THREADS];
    float4 g0 = dg[base]; float4 g1 = dg[base + THREADS];

    unsigned int myc = 0;
#define DO(mm, pp, gg) \
    if (mm != 0.0f) { atomicAdd(&shd[bin_of(pp)], 1); atomicAdd(&shd[bin_of(gg)], -1); ++myc; }
    DO(m0.x, p0.x, g0.x) DO(m0.y, p0.y, g0.y) DO(m0.z, p0.z, g0.z) DO(m0.w, p0.w, g0.w)
    DO(m1.x, p1.x, g1.x) DO(m1.y, p1.y, g1.y) DO(m1.z, p1.z, g1.z) DO(m1.w, p1.w, g1.w)
#undef DO
    if (myc) atomicAdd(&smc, myc);
    __syncthreads();

    // Drain per-block histogram into global difference histogram (device-scope
    // atomics -> coherent at the device point, no fence needed).
    for (int i = t; i < NHIST; i += THREADS) {
        int v = shd[i];
        if (v) atomicAdd(&ws[b * 512 + i], v);
    }
    if (t == 0 && smc) atomicAdd((unsigned int*)&ws[MC_OFF + b], smc);

    // ---- last-arriving-block reduction (fence-free; verified R2) ----
    // Explicit vmcnt drain + barrier: all of this block's global atomics are
    // performed device-wide before the counter bump.
    asm volatile("s_waitcnt vmcnt(0)" ::: "memory");
    __syncthreads();
    if (t == 0) {
        unsigned int old = atomicAdd((unsigned int*)&ws[CTR_OFF], 1u);  // relaxed, device-scope
        lastflag = (old == TOTAL_BLOCKS - 1) ? 1 : 0;
    }
    __syncthreads();
    if (!lastflag) return;

    // Last block (256 threads = 4 waves). Wave w owns batch w: chunked
    // register scan over 512 positions, no LDS, no inter-wave barriers.
    // Agent-scope atomic loads bypass stale local cache lines.
    const int lane = t & 63;
    const int w = t >> 6;
    float acc = 0.0f;
    {
        const unsigned int mc = __hip_atomic_load(
            (unsigned int*)&ws[MC_OFF + w], __ATOMIC_RELAXED, __HIP_MEMORY_SCOPE_AGENT);
        const float denom = (float)mc + 1e-6f;

        // hoist all 8 chunk loads (independent -> overlapped latency)
        int vch[8];
        #pragma unroll
        for (int c = 0; c < 8; ++c) {
            const int idx = c * 64 + lane;
            vch[c] = (idx < NHIST)
                ? __hip_atomic_load(&ws[w * 512 + idx], __ATOMIC_RELAXED,
                                    __HIP_MEMORY_SCOPE_AGENT)
                : 0;
        }
        // sequential carry chain of wave-inclusive scans
        int carry = 0;
        #pragma unroll
        for (int c = 0; c < 8; ++c) {
            int v = vch[c];
            #pragma unroll
            for (int off = 1; off < 64; off <<= 1) {
                int n = __shfl_up(v, off, 64);
                if (lane >= off) v += n;
            }
            v += carry;
            vch[c] = v;                      // inclusive prefix at idx
            carry = __shfl(v, 63, 64);       // running total through chunk
        }
        const int total = carry;             // sum of d[0..500] per batch
        #pragma unroll
        for (int c = 0; c < 8; ++c) {
            const int j = c * 64 + lane;
            if (j < NBINS) {
                // count_ge[j] diff = sum_{k>=j+1} d[k] = total - incl_prefix[j]
                const float diff = (float)(total - vch[c]) / denom;
                acc += diff * diff;
            }
        }
    }

    // wave-local reduce, then cross-wave via LDS
    #pragma unroll
    for (int off = 32; off > 0; off >>= 1) acc += __shfl_down(acc, off, 64);
    if (lane == 0) facc[w] = acc;
    __syncthreads();
    if (t == 0) {
        out[0] = (facc[0] + facc[1] + facc[2] + facc[3]) * (1.0f / (BATCH * NBINS));
    }
}

extern "C" void kernel_launch(void* const* d_in, const int* in_sizes, int n_in,
                              void* d_out, int out_size, void* d_ws, size_t ws_size,
                              hipStream_t stream) {
    const float4* dp = (const float4*)d_in[0];   // d_pred
    const float4* dg = (const float4*)d_in[1];   // d_gt
    const float4* dm = (const float4*)d_in[2];   // mask
    int* ws = (int*)d_ws;

    hipMemsetAsync(d_ws, 0, WS_INTS * sizeof(int), stream);

    dim3 grid(BPB, BATCH);
    dvh_fused_kernel<<<grid, dim3(THREADS), 0, stream>>>(dp, dg, dm, ws, (float*)d_out);
}

// Round 4
// 137.064 us; speedup vs baseline: 1.4818x; 1.4818x over previous
//
#include <hip/hip_runtime.h>
#include <stdint.h>

// DVH global loss, MI355X.
// B=4 batches, N=2^21 voxels/batch, 500 bins over [0,75].
// loss = mean_{b,j} ( suffix_sum_{k>j}(hist_p[b]-hist_g[b])[k] / (maskcount_b+1e-6) )^2
// Only the DIFFERENCE histogram matters: d[i] = hist_p[i] - hist_g[i] (exact in ints).
//
// R1: device fence -> per-wave L2 writeback -> 201 us. Reverted.
// R2: fence-free last-block protocol, 512x1024 -> 41.5 us kernel.
// R3: 4096x256 blocks -> 117 us. WRITE_SIZE 1->8.3 MB exposed the real cost:
//     global atomicAdd drain of per-block hists serializes on 64 cache lines,
//     cost scales with block count (~10-16 us of R2's 41.5 was drain).
// R4: keep 512x1024; replace atomic drain with CONTENTION-FREE per-block
//     partial-hist stores (agent-scope, unique slot per block; 1 MB total).
//     Last block sums 128 partials/batch (coalesced, L3-resident), scans,
//     squares. Memset shrinks to 32 B (maskcount + done counter only).

#define NBINS 500
#define NHIST 501          // searchsorted index c in [0,500]; c>=1 for d>=0
#define BATCH 4
#define NPB (1 << 21)      // elements per batch
#define VPB (NPB / 4)      // float4 per batch
#define THREADS 1024
#define BLOCKS_PER_BATCH 128
#define STRIDE (BLOCKS_PER_BATCH * THREADS)   // 131072 float4s; VPB/STRIDE == 4
#define TOTAL_BLOCKS (BLOCKS_PER_BATCH * BATCH)   // 512

// workspace layout (int32):
//   partial hist : slot s = b*128 + bx, ints [s*512 .. s*512+512)   (512 slots)
//   maskcount    : [PART_INTS + b], b<4
//   done ctr     : [PART_INTS + 4]
#define PART_INTS (TOTAL_BLOCKS * 512)    // 262144 ints = 1 MB
#define MC_OFF PART_INTS
#define CTR_OFF (PART_INTS + 4)
#define ZERO_INTS 8                       // memset covers MC (4) + CTR (1) -> 8

__device__ __forceinline__ int bin_of(float d) {
    // c = # of fp32 bins k*STEP that are <= d  (jnp.linspace(0,75,500),
    // searchsorted side='right'); d >= 0 guaranteed.
    const float STEP = 75.0f / 499.0f;
    const float INV  = 499.0f / 75.0f;
    int k = (int)(d * INV);
    if (k > 499) k = 499;
    if ((float)k * STEP > d) --k;
    else if (k < 499 && (float)(k + 1) * STEP <= d) ++k;
    if ((float)k * STEP > d) --k;   // safety second pass (k>=0 since bins[0]=0<=d)
    return k + 1;                   // in [1,500]
}

__global__ __launch_bounds__(THREADS) void dvh_fused_kernel(
        const float4* __restrict__ dp, const float4* __restrict__ dg,
        const float4* __restrict__ dm, int* __restrict__ ws,
        float* __restrict__ out) {
    __shared__ int shd[512];
    __shared__ unsigned int smc;
    __shared__ int lastflag;
    __shared__ int wtot[2][8];
    __shared__ float facc[16];

    const int b = blockIdx.y;
    const int t = threadIdx.x;
    if (t < 512) shd[t] = 0;
    if (t == 0) smc = 0u;
    __syncthreads();

    // Each thread owns exactly 4 float4s per array. Issue all 12 independent
    // loads before any use -> 12 outstanding vmem ops/thread.
    const size_t base = (size_t)b * VPB + blockIdx.x * THREADS + t;
    float4 m0 = dm[base];              float4 m1 = dm[base + STRIDE];
    float4 m2 = dm[base + 2 * STRIDE]; float4 m3 = dm[base + 3 * STRIDE];
    float4 p0 = dp[base];              float4 p1 = dp[base + STRIDE];
    float4 p2 = dp[base + 2 * STRIDE]; float4 p3 = dp[base + 3 * STRIDE];
    float4 g0 = dg[base];              float4 g1 = dg[base + STRIDE];
    float4 g2 = dg[base + 2 * STRIDE]; float4 g3 = dg[base + 3 * STRIDE];

    unsigned int myc = 0;
#define DO(mm, pp, gg) \
    if (mm != 0.0f) { atomicAdd(&shd[bin_of(pp)], 1); atomicAdd(&shd[bin_of(gg)], -1); ++myc; }
    DO(m0.x, p0.x, g0.x) DO(m0.y, p0.y, g0.y) DO(m0.z, p0.z, g0.z) DO(m0.w, p0.w, g0.w)
    DO(m1.x, p1.x, g1.x) DO(m1.y, p1.y, g1.y) DO(m1.z, p1.z, g1.z) DO(m1.w, p1.w, g1.w)
    DO(m2.x, p2.x, g2.x) DO(m2.y, p2.y, g2.y) DO(m2.z, p2.z, g2.z) DO(m2.w, p2.w, g2.w)
    DO(m3.x, p3.x, g3.x) DO(m3.y, p3.y, g3.y) DO(m3.z, p3.z, g3.z) DO(m3.w, p3.w, g3.w)
#undef DO
    if (myc) atomicAdd(&smc, myc);
    __syncthreads();

    // Contention-free drain: store this block's full 512-bin hist to its own
    // slot. Agent-scope atomic stores -> performed at the coherent point,
    // visible to the last block's agent-scope loads. No serialization.
    {
        const int slot = b * BLOCKS_PER_BATCH + blockIdx.x;
        if (t < 512) {
            __hip_atomic_store(&ws[slot * 512 + t], shd[t],
                               __ATOMIC_RELAXED, __HIP_MEMORY_SCOPE_AGENT);
        }
    }
    if (t == 0 && smc) atomicAdd((unsigned int*)&ws[MC_OFF + b], smc);

    // ---- last-arriving-block protocol (fence-free; verified R2) ----
    // Explicit vmcnt drain + barrier: all of this block's stores/atomics are
    // performed device-wide before the counter bump.
    asm volatile("s_waitcnt vmcnt(0)" ::: "memory");
    __syncthreads();
    if (t == 0) {
        unsigned int old = atomicAdd((unsigned int*)&ws[CTR_OFF], 1u);
        lastflag = (old == TOTAL_BLOCKS - 1) ? 1 : 0;
    }
    __syncthreads();
    if (!lastflag) return;

    // Last block: sum 128 partials per batch, scan, suffix, square.
    // Thread layout: half h = t>>9 handles batches {2h, 2h+1}; bin j = t&511.
    const int lane = t & 63;
    const int w = t >> 6;          // global wave 0..15
    const int h = t >> 9;          // half 0/1
    const int j = t & 511;         // bin index within half
    const int wl = (t >> 6) & 7;   // wave within half 0..7
    float acc = 0.0f;

    #pragma unroll
    for (int bi = 0; bi < 2; ++bi) {
        const int bb = h * 2 + bi;
        // coalesced column sum over the 128 partials of batch bb
        int s = 0;
        const int pb = bb * BLOCKS_PER_BATCH * 512 + j;
        #pragma unroll 8
        for (int k = 0; k < BLOCKS_PER_BATCH; ++k) {
            s += __hip_atomic_load(&ws[pb + k * 512],
                                   __ATOMIC_RELAXED, __HIP_MEMORY_SCOPE_AGENT);
        }
        // inclusive scan over the 512 threads of this half
        int v = s;
        #pragma unroll
        for (int off = 1; off < 64; off <<= 1) {
            int n = __shfl_up(v, off, 64);
            if (lane >= off) v += n;
        }
        if (lane == 63) wtot[h][wl] = v;
        __syncthreads();
        int offset = 0, total = 0;
        #pragma unroll
        for (int i = 0; i < 8; ++i) {
            int x = wtot[h][i];
            total += x;
            if (i < wl) offset += x;
        }
        const int prefix = v + offset;   // inclusive prefix over d[0..j]
        const unsigned int mc = __hip_atomic_load(
            (unsigned int*)&ws[MC_OFF + bb], __ATOMIC_RELAXED,
            __HIP_MEMORY_SCOPE_AGENT);
        const float denom = (float)mc + 1e-6f;
        if (j < NBINS) {
            // count_ge[j] diff = sum_{k>=j+1} d[k] = total - incl_prefix[j]
            const float diff = (float)(total - prefix) / denom;
            acc += diff * diff;
        }
        __syncthreads();   // before wtot reuse next iteration
    }

    // block reduction of acc
    #pragma unroll
    for (int off = 32; off > 0; off >>= 1) acc += __shfl_down(acc, off, 64);
    if (lane == 0) facc[w] = acc;
    __syncthreads();
    if (t == 0) {
        float ssum = 0.0f;
        #pragma unroll
        for (int i = 0; i < 16; ++i) ssum += facc[i];
        out[0] = ssum * (1.0f / (BATCH * NBINS));
    }
}

extern "C" void kernel_launch(void* const* d_in, const int* in_sizes, int n_in,
                              void* d_out, int out_size, void* d_ws, size_t ws_size,
                              hipStream_t stream) {
    const float4* dp = (const float4*)d_in[0];   // d_pred
    const float4* dg = (const float4*)d_in[1];   // d_gt
    const float4* dm = (const float4*)d_in[2];   // mask
    int* ws = (int*)d_ws;

    // Partials are fully overwritten each iteration (unconditional stores);
    // only maskcount + done counter need zeroing.
    hipMemsetAsync(ws + MC_OFF, 0, ZERO_INTS * sizeof(int), stream);

    dim3 grid(BLOCKS_PER_BATCH, BATCH);
    dvh_fused_kernel<<<grid, dim3(THREADS), 0, stream>>>(dp, dg, dm, ws, (float*)d_out);
}

// Round 5
// 127.471 us; speedup vs baseline: 1.5933x; 1.0753x over previous
//
#include <hip/hip_runtime.h>
#include <stdint.h>

// DVH global loss, MI355X.
// B=4 batches, N=2^21 voxels/batch, 500 bins over [0,75].
// loss = mean_{b,j} ( suffix_sum_{k>j}(hist_p[b]-hist_g[b])[k] / (maskcount_b+1e-6) )^2
// Only the DIFFERENCE histogram matters: d[i] = hist_p[i] - hist_g[i] (exact in ints).
//
// R1: device fence -> per-wave L2 writeback -> 201 us. Reverted.
// R2: fence-free last-block protocol, 512x1024, atomic drain -> 41.5 us kernel.
// R3: 4096x256 -> 117 us: atomic drain serializes on the 4x2KB hot regions,
//     cost scales with block count.
// R4: contention-free per-block partial stores -> drain cheap, but last block
//     reads 1 MB alone (single-CU ~100-150 GB/s) = 7-12 us serial tail; net loss.
// R5: middle ground. 8 REPLICA histograms per batch (rep = blockIdx.x & 7):
//     8x less atomic contention per hot region than R2, last-block merge reads
//     only 64 KB (~1 us). Load issue order interleaved (m,p,g per chunk) so
//     chunk-0 compute starts after 3 deliveries, overlapping the other 9.

#define NBINS 500
#define NHIST 501          // searchsorted index c in [0,500]; c>=1 for d>=0
#define BATCH 4
#define NPB (1 << 21)      // elements per batch
#define VPB (NPB / 4)      // float4 per batch
#define THREADS 1024
#define BLOCKS_PER_BATCH 128
#define STRIDE (BLOCKS_PER_BATCH * THREADS)   // 131072 float4s; VPB/STRIDE == 4
#define TOTAL_BLOCKS (BLOCKS_PER_BATCH * BATCH)   // 512
#define REPS 8             // replica histograms per batch

// workspace layout (int32):
//   replica hists : [(b*REPS + r)*512 + i], i<512, r<8, b<4   (16384 ints)
//   maskcount     : [16384 + b]
//   done ctr      : [16388]
#define HIST_INTS (BATCH * REPS * 512)
#define MC_OFF HIST_INTS
#define CTR_OFF (HIST_INTS + 4)
#define ZERO_INTS (HIST_INTS + 8)

__device__ __forceinline__ int bin_of(float d) {
    // c = # of fp32 bins k*STEP that are <= d  (jnp.linspace(0,75,500),
    // searchsorted side='right'); d >= 0 guaranteed.
    const float STEP = 75.0f / 499.0f;
    const float INV  = 499.0f / 75.0f;
    int k = (int)(d * INV);
    if (k > 499) k = 499;
    if ((float)k * STEP > d) --k;
    else if (k < 499 && (float)(k + 1) * STEP <= d) ++k;
    if ((float)k * STEP > d) --k;   // safety second pass (k>=0 since bins[0]=0<=d)
    return k + 1;                   // in [1,500]
}

__global__ __launch_bounds__(THREADS) void dvh_fused_kernel(
        const float4* __restrict__ dp, const float4* __restrict__ dg,
        const float4* __restrict__ dm, int* __restrict__ ws,
        float* __restrict__ out) {
    __shared__ int shd[512];
    __shared__ unsigned int smc;
    __shared__ int lastflag;
    __shared__ int wtot[2][8];
    __shared__ float facc[16];

    const int b = blockIdx.y;
    const int t = threadIdx.x;
    if (t < 512) shd[t] = 0;
    if (t == 0) smc = 0u;
    __syncthreads();

    // 12 independent loads, all issued before first use (max MLP). Issue order
    // interleaved by chunk: first DO chunk needs only the first 3 deliveries.
    const size_t base = (size_t)b * VPB + blockIdx.x * THREADS + t;
    float4 m0 = dm[base];              float4 p0 = dp[base];              float4 g0 = dg[base];
    float4 m1 = dm[base + STRIDE];     float4 p1 = dp[base + STRIDE];     float4 g1 = dg[base + STRIDE];
    float4 m2 = dm[base + 2 * STRIDE]; float4 p2 = dp[base + 2 * STRIDE]; float4 g2 = dg[base + 2 * STRIDE];
    float4 m3 = dm[base + 3 * STRIDE]; float4 p3 = dp[base + 3 * STRIDE]; float4 g3 = dg[base + 3 * STRIDE];

    unsigned int myc = 0;
#define DO(mm, pp, gg) \
    if (mm != 0.0f) { atomicAdd(&shd[bin_of(pp)], 1); atomicAdd(&shd[bin_of(gg)], -1); ++myc; }
    DO(m0.x, p0.x, g0.x) DO(m0.y, p0.y, g0.y) DO(m0.z, p0.z, g0.z) DO(m0.w, p0.w, g0.w)
    DO(m1.x, p1.x, g1.x) DO(m1.y, p1.y, g1.y) DO(m1.z, p1.z, g1.z) DO(m1.w, p1.w, g1.w)
    DO(m2.x, p2.x, g2.x) DO(m2.y, p2.y, g2.y) DO(m2.z, p2.z, g2.z) DO(m2.w, p2.w, g2.w)
    DO(m3.x, p3.x, g3.x) DO(m3.y, p3.y, g3.y) DO(m3.z, p3.z, g3.z) DO(m3.w, p3.w, g3.w)
#undef DO
    if (myc) atomicAdd(&smc, myc);
    __syncthreads();

    // Drain into one of 8 replica histograms for this batch: 8x less atomic
    // contention per hot region than a single merged hist; still only 64 KB
    // total for the last block to merge.
    {
        const int rep = blockIdx.x & (REPS - 1);
        int* dst = &ws[(b * REPS + rep) * 512];
        if (t < 512) {
            int v = shd[t];
            if (v) atomicAdd(&dst[t], v);
        }
    }
    if (t == 0 && smc) atomicAdd((unsigned int*)&ws[MC_OFF + b], smc);

    // ---- last-arriving-block protocol (fence-free; verified R2/R4) ----
    // Explicit vmcnt drain + barrier: all of this block's atomics are
    // performed device-wide before the counter bump.
    asm volatile("s_waitcnt vmcnt(0)" ::: "memory");
    __syncthreads();
    if (t == 0) {
        unsigned int old = atomicAdd((unsigned int*)&ws[CTR_OFF], 1u);
        lastflag = (old == TOTAL_BLOCKS - 1) ? 1 : 0;
    }
    __syncthreads();
    if (!lastflag) return;

    // Last block: merge 8 replicas per batch (64 KB total), scan, suffix, square.
    // Thread layout: half h = t>>9 handles batches {2h, 2h+1}; bin j = t&511.
    const int lane = t & 63;
    const int w = t >> 6;          // global wave 0..15
    const int h = t >> 9;          // half 0/1
    const int j = t & 511;         // bin index within half
    const int wl = (t >> 6) & 7;   // wave within half 0..7
    float acc = 0.0f;

    #pragma unroll
    for (int bi = 0; bi < 2; ++bi) {
        const int bb = h * 2 + bi;
        // merge replicas (agent-scope loads bypass stale local cache lines)
        int s = 0;
        const int pb = (bb * REPS) * 512 + j;
        #pragma unroll
        for (int r = 0; r < REPS; ++r) {
            s += __hip_atomic_load(&ws[pb + r * 512],
                                   __ATOMIC_RELAXED, __HIP_MEMORY_SCOPE_AGENT);
        }
        // inclusive scan over the 512 threads of this half
        int v = s;
        #pragma unroll
        for (int off = 1; off < 64; off <<= 1) {
            int n = __shfl_up(v, off, 64);
            if (lane >= off) v += n;
        }
        if (lane == 63) wtot[h][wl] = v;
        __syncthreads();
        int offset = 0, total = 0;
        #pragma unroll
        for (int i = 0; i < 8; ++i) {
            int x = wtot[h][i];
            total += x;
            if (i < wl) offset += x;
        }
        const int prefix = v + offset;   // inclusive prefix over d[0..j]
        const unsigned int mc = __hip_atomic_load(
            (unsigned int*)&ws[MC_OFF + bb], __ATOMIC_RELAXED,
            __HIP_MEMORY_SCOPE_AGENT);
        const float denom = (float)mc + 1e-6f;
        if (j < NBINS) {
            // count_ge[j] diff = sum_{k>=j+1} d[k] = total - incl_prefix[j]
            const float diff = (float)(total - prefix) / denom;
            acc += diff * diff;
        }
        __syncthreads();   // before wtot reuse next iteration
    }

    // block reduction of acc
    #pragma unroll
    for (int off = 32; off > 0; off >>= 1) acc += __shfl_down(acc, off, 64);
    if (lane == 0) facc[w] = acc;
    __syncthreads();
    if (t == 0) {
        float ssum = 0.0f;
        #pragma unroll
        for (int i = 0; i < 16; ++i) ssum += facc[i];
        out[0] = ssum * (1.0f / (BATCH * NBINS));
    }
}

extern "C" void kernel_launch(void* const* d_in, const int* in_sizes, int n_in,
                              void* d_out, int out_size, void* d_ws, size_t ws_size,
                              hipStream_t stream) {
    const float4* dp = (const float4*)d_in[0];   // d_pred
    const float4* dg = (const float4*)d_in[1];   // d_gt
    const float4* dm = (const float4*)d_in[2];   // mask
    int* ws = (int*)d_ws;

    hipMemsetAsync(ws, 0, ZERO_INTS * sizeof(int), stream);

    dim3 grid(BLOCKS_PER_BATCH, BATCH);
    dvh_fused_kernel<<<grid, dim3(THREADS), 0, stream>>>(dp, dg, dm, ws, (float*)d_out);
}

// Round 6
// 124.291 us; speedup vs baseline: 1.6341x; 1.0256x over previous
//
#include <hip/hip_runtime.h>
#include <stdint.h>

// DVH global loss, MI355X.
// B=4 batches, N=2^21 voxels/batch, 500 bins over [0,75].
// loss = mean_{b,j} ( suffix_sum_{k>j}(hist_p[b]-hist_g[b])[k] / (maskcount_b+1e-6) )^2
// Only the DIFFERENCE histogram matters: d[i] = hist_p[i] - hist_g[i] (exact in ints).
//
// R1: device fence -> per-wave L2 writeback -> 201 us. Reverted.
// R2: fence-free last-block protocol, 512x1024, atomic drain -> 41.5 us kernel.
// R3: 4096x256 -> 117 us: drain atomics scale with block count. Few fat blocks.
// R4: per-block partial stores -> 1 MB single-block merge tail = 7-12 us. Reverted.
// R5: 8-replica drain -> neutral (44 us). Ledger: drain small, tail small,
//     MAIN PHASE = ~40 us vs ~16 us delivery floor + 9 us VALU.
// R6: VGPR_Count=28 proved the compiler SANK the 12 upfront loads (48 VGPRs of
//     payload can't fit in 28) -> emitted code is serial {load3,wait,compute}x4
//     with all waves in lockstep -> ~4x exposed vmem latency = the missing 25 us.
//     Fix: depth-3 software pipeline, explicit named regs, sched_barrier(0)
//     pins after each load group so regalloc MUST keep payloads live.
//     Verify via VGPR_Count ~50-60 in counters.

#define NBINS 500
#define NHIST 501          // searchsorted index c in [0,500]; c>=1 for d>=0
#define BATCH 4
#define NPB (1 << 21)      // elements per batch
#define VPB (NPB / 4)      // float4 per batch
#define THREADS 1024
#define BLOCKS_PER_BATCH 128
#define STRIDE (BLOCKS_PER_BATCH * THREADS)   // 131072 float4s; VPB/STRIDE == 4
#define TOTAL_BLOCKS (BLOCKS_PER_BATCH * BATCH)   // 512
#define REPS 8             // replica histograms per batch

// workspace layout (int32):
//   replica hists : [(b*REPS + r)*512 + i], i<512, r<8, b<4   (16384 ints)
//   maskcount     : [16384 + b]
//   done ctr      : [16388]
#define HIST_INTS (BATCH * REPS * 512)
#define MC_OFF HIST_INTS
#define CTR_OFF (HIST_INTS + 4)
#define ZERO_INTS (HIST_INTS + 8)

__device__ __forceinline__ int bin_of(float d) {
    // c = # of fp32 bins k*STEP that are <= d  (jnp.linspace(0,75,500),
    // searchsorted side='right'); d >= 0 guaranteed.
    const float STEP = 75.0f / 499.0f;
    const float INV  = 499.0f / 75.0f;
    int k = (int)(d * INV);
    if (k > 499) k = 499;
    if ((float)k * STEP > d) --k;
    else if (k < 499 && (float)(k + 1) * STEP <= d) ++k;
    if ((float)k * STEP > d) --k;   // safety second pass (k>=0 since bins[0]=0<=d)
    return k + 1;                   // in [1,500]
}

__global__ __launch_bounds__(THREADS) void dvh_fused_kernel(
        const float4* __restrict__ dp, const float4* __restrict__ dg,
        const float4* __restrict__ dm, int* __restrict__ ws,
        float* __restrict__ out) {
    __shared__ int shd[512];
    __shared__ unsigned int smc;
    __shared__ int lastflag;
    __shared__ int wtot[2][8];
    __shared__ float facc[16];

    const int b = blockIdx.y;
    const int t = threadIdx.x;
    if (t < 512) shd[t] = 0;
    if (t == 0) smc = 0u;
    __syncthreads();

    const size_t base = (size_t)b * VPB + blockIdx.x * THREADS + t;

    // ---- depth-3 software pipeline over 4 chunks ----
    // Prologue: chunks 0,1,2 in flight (9 loads, 36 VGPRs payload).
    float4 mA = dm[base];              float4 pA = dp[base];              float4 gA = dg[base];
    float4 mB = dm[base + STRIDE];     float4 pB = dp[base + STRIDE];     float4 gB = dg[base + STRIDE];
    float4 mC = dm[base + 2 * STRIDE]; float4 pC = dp[base + 2 * STRIDE]; float4 gC = dg[base + 2 * STRIDE];
    __builtin_amdgcn_sched_barrier(0);   // pin: all 9 loads issued before any use

    unsigned int myc = 0;
#define DO(mm, pp, gg) \
    if (mm != 0.0f) { atomicAdd(&shd[bin_of(pp)], 1); atomicAdd(&shd[bin_of(gg)], -1); ++myc; }
#define PROC(MM, PP, GG) \
    DO(MM.x, PP.x, GG.x) DO(MM.y, PP.y, GG.y) DO(MM.z, PP.z, GG.z) DO(MM.w, PP.w, GG.w)

    // chunk 0 (waits only its own 3 loads; 6 still in flight)
    PROC(mA, pA, gA)
    // issue chunk 3 while chunks 1,2 are still in flight / being consumed
    float4 mD = dm[base + 3 * STRIDE]; float4 pD = dp[base + 3 * STRIDE]; float4 gD = dg[base + 3 * STRIDE];
    __builtin_amdgcn_sched_barrier(0);   // pin: chunk-3 loads issued before chunk-1 compute
    PROC(mB, pB, gB)
    PROC(mC, pC, gC)
    PROC(mD, pD, gD)
#undef PROC
#undef DO

    if (myc) atomicAdd(&smc, myc);
    __syncthreads();

    // Drain into one of 8 replica histograms for this batch (R5-verified:
    // contention spread, 64 KB total merge for last block).
    {
        const int rep = blockIdx.x & (REPS - 1);
        int* dst = &ws[(b * REPS + rep) * 512];
        if (t < 512) {
            int v = shd[t];
            if (v) atomicAdd(&dst[t], v);
        }
    }
    if (t == 0 && smc) atomicAdd((unsigned int*)&ws[MC_OFF + b], smc);

    // ---- last-arriving-block protocol (fence-free; verified R2/R4/R5) ----
    asm volatile("s_waitcnt vmcnt(0)" ::: "memory");
    __syncthreads();
    if (t == 0) {
        unsigned int old = atomicAdd((unsigned int*)&ws[CTR_OFF], 1u);
        lastflag = (old == TOTAL_BLOCKS - 1) ? 1 : 0;
    }
    __syncthreads();
    if (!lastflag) return;

    // Last block: merge 8 replicas per batch (64 KB total), scan, suffix, square.
    // Thread layout: half h = t>>9 handles batches {2h, 2h+1}; bin j = t&511.
    const int lane = t & 63;
    const int w = t >> 6;          // global wave 0..15
    const int h = t >> 9;          // half 0/1
    const int j = t & 511;         // bin index within half
    const int wl = (t >> 6) & 7;   // wave within half 0..7
    float acc = 0.0f;

    #pragma unroll
    for (int bi = 0; bi < 2; ++bi) {
        const int bb = h * 2 + bi;
        // merge replicas (agent-scope loads bypass stale local cache lines)
        int s = 0;
        const int pb = (bb * REPS) * 512 + j;
        #pragma unroll
        for (int r = 0; r < REPS; ++r) {
            s += __hip_atomic_load(&ws[pb + r * 512],
                                   __ATOMIC_RELAXED, __HIP_MEMORY_SCOPE_AGENT);
        }
        // inclusive scan over the 512 threads of this half
        int v = s;
        #pragma unroll
        for (int off = 1; off < 64; off <<= 1) {
            int n = __shfl_up(v, off, 64);
            if (lane >= off) v += n;
        }
        if (lane == 63) wtot[h][wl] = v;
        __syncthreads();
        int offset = 0, total = 0;
        #pragma unroll
        for (int i = 0; i < 8; ++i) {
            int x = wtot[h][i];
            total += x;
            if (i < wl) offset += x;
        }
        const int prefix = v + offset;   // inclusive prefix over d[0..j]
        const unsigned int mc = __hip_atomic_load(
            (unsigned int*)&ws[MC_OFF + bb], __ATOMIC_RELAXED,
            __HIP_MEMORY_SCOPE_AGENT);
        const float denom = (float)mc + 1e-6f;
        if (j < NBINS) {
            // count_ge[j] diff = sum_{k>=j+1} d[k] = total - incl_prefix[j]
            const float diff = (float)(total - prefix) / denom;
            acc += diff * diff;
        }
        __syncthreads();   // before wtot reuse next iteration
    }

    // block reduction of acc
    #pragma unroll
    for (int off = 32; off > 0; off >>= 1) acc += __shfl_down(acc, off, 64);
    if (lane == 0) facc[w] = acc;
    __syncthreads();
    if (t == 0) {
        float ssum = 0.0f;
        #pragma unroll
        for (int i = 0; i < 16; ++i) ssum += facc[i];
        out[0] = ssum * (1.0f / (BATCH * NBINS));
    }
}

extern "C" void kernel_launch(void* const* d_in, const int* in_sizes, int n_in,
                              void* d_out, int out_size, void* d_ws, size_t ws_size,
                              hipStream_t stream) {
    const float4* dp = (const float4*)d_in[0];   // d_pred
    const float4* dg = (const float4*)d_in[1];   // d_gt
    const float4* dm = (const float4*)d_in[2];   // mask
    int* ws = (int*)d_ws;

    hipMemsetAsync(ws, 0, ZERO_INTS * sizeof(int), stream);

    dim3 grid(BLOCKS_PER_BATCH, BATCH);
    dvh_fused_kernel<<<grid, dim3(THREADS), 0, stream>>>(dp, dg, dm, ws, (float*)d_out);
}